// Round 1
// baseline (1997.304 us; speedup 1.0000x reference)
//
#include <hip/hip_runtime.h>
#include <hip/hip_bf16.h>
#include <math.h>

// ---------------- types / helpers ----------------
typedef __attribute__((ext_vector_type(8))) __bf16 bf16x8;
typedef __attribute__((ext_vector_type(4))) float  f32x4;

__device__ __forceinline__ unsigned short f2bf(float f) {
    union { float f; unsigned int u; } x; x.f = f;
    unsigned int r = x.u + 0x7fffu + ((x.u >> 16) & 1u);   // RTNE
    return (unsigned short)(r >> 16);
}

#define B_   4
#define C_   512
#define T_   4096
#define CO3  1536
#define NH   4
#define DH   128

// ---------------- weight converts (permute [co][ci][k] -> [co][k][ci], fp32->bf16) ----------------
__global__ __launch_bounds__(256) void cvt_wqkv(const float* __restrict__ w, unsigned short* __restrict__ o) {
    __shared__ unsigned short l[512 * 33];          // stride 33 breaks bank conflicts
    int co = blockIdx.x;
    const float* src = w + (size_t)co * 16384;
    for (int j = 0; j < 64; j++) {
        int i = threadIdx.x + j * 256;              // i = ci*32 + dk (input layout)
        l[(i >> 5) * 33 + (i & 31)] = f2bf(src[i]);
    }
    __syncthreads();
    unsigned short* dst = o + (size_t)co * 16384;
    for (int j = 0; j < 64; j++) {
        int i = threadIdx.x + j * 256;              // i = dk*512 + ci (output layout)
        int dk = i >> 9, ci = i & 511;
        dst[i] = l[ci * 33 + dk];
    }
}

__global__ __launch_bounds__(256) void cvt_wproj(const float* __restrict__ w, unsigned short* __restrict__ o) {
    __shared__ unsigned short l[512 * 6];
    int co = blockIdx.x;
    const float* src = w + (size_t)co * 2560;
    for (int j = 0; j < 10; j++) {
        int i = threadIdx.x + j * 256;              // i = ci*5 + dk
        int ci = i / 5, dk = i - ci * 5;
        l[ci * 6 + dk] = f2bf(src[i]);
    }
    __syncthreads();
    unsigned short* dst = o + (size_t)co * 2560;
    for (int j = 0; j < 10; j++) {
        int i = threadIdx.x + j * 256;              // i = dk*512 + ci
        int dk = i >> 9, ci = i & 511;
        dst[i] = l[ci * 6 + dk];
    }
}

// ---------------- GroupNorm -> bf16, stored t-major gnT[b][t][c] ----------------
__global__ __launch_bounds__(1024) void groupnorm(const float* __restrict__ x,
                                                  const float* __restrict__ gamma,
                                                  const float* __restrict__ beta,
                                                  unsigned short* __restrict__ gnT) {
    int g = blockIdx.x, b = blockIdx.y;
    int tid = threadIdx.x;
    const float* base = x + ((size_t)b * C_ + g * 16) * T_;   // 16 ch x 4096
    float s = 0.f, s2 = 0.f;
    const float4* b4 = (const float4*)base;
    for (int j = 0; j < 16; j++) {
        float4 v = b4[tid + j * 1024];
        s  += v.x + v.y + v.z + v.w;
        s2 += v.x * v.x + v.y * v.y + v.z * v.z + v.w * v.w;
    }
    for (int off = 32; off; off >>= 1) { s += __shfl_down(s, off, 64); s2 += __shfl_down(s2, off, 64); }
    __shared__ float red[34];
    int wid = tid >> 6, lane = tid & 63;
    if (lane == 0) { red[wid] = s; red[16 + wid] = s2; }
    __syncthreads();
    if (tid == 0) {
        float ts = 0.f, ts2 = 0.f;
        for (int i = 0; i < 16; i++) { ts += red[i]; ts2 += red[16 + i]; }
        float mu = ts / 65536.f;
        float var = ts2 / 65536.f - mu * mu;
        red[32] = mu; red[33] = rsqrtf(var + 1e-5f);
    }
    __syncthreads();
    float mu = red[32], inv = red[33];
    for (int p = 0; p < 4; p++) {
        int t = tid + p * 1024;
        unsigned short outv[16];
        for (int cc = 0; cc < 16; cc++) {
            float xv = base[(size_t)cc * T_ + t];
            int c = g * 16 + cc;
            outv[cc] = f2bf((xv - mu) * inv * gamma[c] + beta[c]);
        }
        unsigned short* dst = gnT + ((size_t)b * T_ + t) * C_ + g * 16;
        *(uint4*)dst       = *(uint4*)outv;
        *(uint4*)(dst + 8) = *(uint4*)(outv + 8);
    }
}

// ---------------- QKV conv as GEMM: C[co=1536][t=4096] per batch, K = dk(32) x ci(512) ----------------
// outputs scattered into attention layouts: qT/kT[bh][t][c(128)], v[bh][c(128)][t]
__global__ __launch_bounds__(256) void gemm_qkv(const unsigned short* __restrict__ gnT,
                                                const unsigned short* __restrict__ wq,   // [co][dk][ci] bf16
                                                const float* __restrict__ bias,
                                                unsigned short* __restrict__ qT,
                                                unsigned short* __restrict__ kT,
                                                unsigned short* __restrict__ vv) {
    int nblk = blockIdx.x, mblk = blockIdx.y, b = blockIdx.z;
    int m0 = mblk * 128, t0 = nblk * 128;
    __shared__ unsigned short As[128 * 32];   // [m][k]
    __shared__ unsigned short Bs[128 * 32];   // [n=t][k=ci]
    int tid = threadIdx.x, lane = tid & 63, wave = tid >> 6;
    int quad = lane >> 4, l16 = lane & 15;
    int wm = wave & 1, wn = wave >> 1;
    f32x4 acc[4][4];
    f32x4 z4 = {0.f, 0.f, 0.f, 0.f};
    for (int mt = 0; mt < 4; mt++) for (int nt = 0; nt < 4; nt++) acc[mt][nt] = z4;

    int srow = tid >> 1, scol = (tid & 1) * 16;
    const unsigned short* gb = gnT + (size_t)b * T_ * C_;
    for (int dk = 0; dk < 32; dk++) {
        int trow = t0 + dk - 15 + srow;
        bool inb = (unsigned)trow < (unsigned)T_;
        const unsigned short* bsrc = gb + (size_t)trow * C_ + scol;
        const unsigned short* asrc = wq + (size_t)(m0 + srow) * 16384 + dk * 512 + scol;
        for (int ci0 = 0; ci0 < 512; ci0 += 32) {
            __syncthreads();
            uint4 a0 = *(const uint4*)(asrc + ci0);
            uint4 a1 = *(const uint4*)(asrc + ci0 + 8);
            uint4 b0 = make_uint4(0, 0, 0, 0), b1 = make_uint4(0, 0, 0, 0);
            if (inb) { b0 = *(const uint4*)(bsrc + ci0); b1 = *(const uint4*)(bsrc + ci0 + 8); }
            *(uint4*)&As[srow * 32 + scol]     = a0;
            *(uint4*)&As[srow * 32 + scol + 8] = a1;
            *(uint4*)&Bs[srow * 32 + scol]     = b0;
            *(uint4*)&Bs[srow * 32 + scol + 8] = b1;
            __syncthreads();
            bf16x8 af[4], bfr[4];
            for (int mt = 0; mt < 4; mt++) af[mt]  = *(const bf16x8*)&As[(wm * 64 + mt * 16 + l16) * 32 + quad * 8];
            for (int nt = 0; nt < 4; nt++) bfr[nt] = *(const bf16x8*)&Bs[(wn * 64 + nt * 16 + l16) * 32 + quad * 8];
            for (int mt = 0; mt < 4; mt++)
                for (int nt = 0; nt < 4; nt++)
                    acc[mt][nt] = __builtin_amdgcn_mfma_f32_16x16x32_bf16(af[mt], bfr[nt], acc[mt][nt], 0, 0, 0);
        }
    }
    // epilogue: bias + bf16 + scatter to q/k/v layouts
    for (int mt = 0; mt < 4; mt++) {
        int cobase = m0 + wm * 64 + mt * 16 + quad * 4;     // rows cobase..cobase+3
        int h = cobase / 384;
        int local = cobase - h * 384;
        int bh = b * NH + h;
        for (int nt = 0; nt < 4; nt++) {
            int t = t0 + wn * 64 + nt * 16 + l16;
            f32x4 a = acc[mt][nt];
            unsigned short r4[4];
            for (int r = 0; r < 4; r++) r4[r] = f2bf(a[r] + bias[cobase + r]);
            if (local < 128) {
                unsigned short* dst = qT + ((size_t)bh * T_ + t) * DH + local;
                *(uint2*)dst = *(uint2*)r4;
            } else if (local < 256) {
                unsigned short* dst = kT + ((size_t)bh * T_ + t) * DH + (local - 128);
                *(uint2*)dst = *(uint2*)r4;
            } else {
                unsigned short* dst = vv + ((size_t)bh * DH + (local - 256)) * T_ + t;
                for (int r = 0; r < 4; r++) dst[(size_t)r * T_] = r4[r];
            }
        }
    }
}

// ---------------- flash attention: 64-query tile, online softmax ----------------
__global__ __launch_bounds__(256) void attn(const unsigned short* __restrict__ qT,
                                            const unsigned short* __restrict__ kT,
                                            const unsigned short* __restrict__ vv,
                                            unsigned short* __restrict__ hT) {
    int q0 = blockIdx.x * 64, bh = blockIdx.y;
    int b = bh >> 2, h = bh & 3;
    __shared__ unsigned short Qs[64 * 128], Ks[64 * 128], Vs[128 * 64], Ps[64 * 64];
    int tid = threadIdx.x, lane = tid & 63, wave = tid >> 6, quad = lane >> 4, l16 = lane & 15;
    {
        int row = tid >> 4, col = (tid & 15) * 8;
        for (int p = 0; p < 4; p++)
            *(uint4*)&Qs[(row + p * 16) * 128 + col] =
                *(const uint4*)&qT[((size_t)bh * T_ + q0 + row + p * 16) * DH + col];
    }
    float m_i[4], l_i[4];
    for (int r = 0; r < 4; r++) { m_i[r] = -1e30f; l_i[r] = 0.f; }
    f32x4 z4 = {0.f, 0.f, 0.f, 0.f};
    f32x4 o[8];
    for (int nt = 0; nt < 8; nt++) o[nt] = z4;
    const float scale2 = 0.08838834764831845f;   // 128^-0.5 = (128^-0.25)^2

    for (int ts0 = 0; ts0 < T_; ts0 += 64) {
        __syncthreads();
        {
            int row = tid >> 4, col = (tid & 15) * 8;
            for (int p = 0; p < 4; p++)
                *(uint4*)&Ks[(row + p * 16) * 128 + col] =
                    *(const uint4*)&kT[((size_t)bh * T_ + ts0 + row + p * 16) * DH + col];
            int c = tid >> 3, col2 = (tid & 7) * 8;
            for (int p = 0; p < 4; p++)
                *(uint4*)&Vs[(c + p * 32) * 64 + col2] =
                    *(const uint4*)&vv[((size_t)bh * DH + c + p * 32) * T_ + ts0 + col2];
        }
        __syncthreads();
        f32x4 s[4];
        for (int nt = 0; nt < 4; nt++) s[nt] = z4;
        for (int kk = 0; kk < 4; kk++) {
            bf16x8 af = *(const bf16x8*)&Qs[(wave * 16 + l16) * 128 + kk * 32 + quad * 8];
            for (int nt = 0; nt < 4; nt++) {
                bf16x8 bfr = *(const bf16x8*)&Ks[(nt * 16 + l16) * 128 + kk * 32 + quad * 8];
                s[nt] = __builtin_amdgcn_mfma_f32_16x16x32_bf16(af, bfr, s[nt], 0, 0, 0);
            }
        }
        for (int nt = 0; nt < 4; nt++) s[nt] *= scale2;
        for (int r = 0; r < 4; r++) {
            float mx = fmaxf(fmaxf(s[0][r], s[1][r]), fmaxf(s[2][r], s[3][r]));
            for (int off = 1; off < 16; off <<= 1) mx = fmaxf(mx, __shfl_xor(mx, off, 64));
            float mnew = fmaxf(m_i[r], mx);
            float alpha = __expf(m_i[r] - mnew);
            m_i[r] = mnew;
            float rs = 0.f;
            for (int nt = 0; nt < 4; nt++) { float p = __expf(s[nt][r] - mnew); s[nt][r] = p; rs += p; }
            for (int off = 1; off < 16; off <<= 1) rs += __shfl_xor(rs, off, 64);
            l_i[r] = l_i[r] * alpha + rs;
            for (int nt = 0; nt < 8; nt++) o[nt][r] *= alpha;
            int prow = wave * 16 + quad * 4 + r;
            for (int nt = 0; nt < 4; nt++) Ps[prow * 64 + nt * 16 + l16] = f2bf(s[nt][r]);
        }
        __syncthreads();
        for (int kk = 0; kk < 2; kk++) {
            bf16x8 af = *(const bf16x8*)&Ps[(wave * 16 + l16) * 64 + kk * 32 + quad * 8];
            for (int nt = 0; nt < 8; nt++) {
                bf16x8 bfr = *(const bf16x8*)&Vs[(nt * 16 + l16) * 64 + kk * 32 + quad * 8];
                o[nt] = __builtin_amdgcn_mfma_f32_16x16x32_bf16(af, bfr, o[nt], 0, 0, 0);
            }
        }
    }
    for (int r = 0; r < 4; r++) {
        float invl = 1.0f / l_i[r];
        int t = q0 + wave * 16 + quad * 4 + r;
        unsigned short* dst = hT + ((size_t)b * T_ + t) * C_ + h * DH;
        for (int nt = 0; nt < 8; nt++) dst[nt * 16 + l16] = f2bf(o[nt][r] * invl);
    }
}

// ---------------- proj conv as GEMM (k=5) + bias + residual, fp32 out ----------------
__global__ __launch_bounds__(256) void gemm_proj(const unsigned short* __restrict__ hT,  // [b][t][c] bf16
                                                 const unsigned short* __restrict__ wp,  // [co][dk(5)][ci] bf16
                                                 const float* __restrict__ bias,
                                                 const float* __restrict__ x,
                                                 float* __restrict__ out) {
    int nblk = blockIdx.x, mblk = blockIdx.y, b = blockIdx.z;
    int m0 = mblk * 128, t0 = nblk * 128;
    __shared__ unsigned short As[128 * 32], Bs[128 * 32];
    int tid = threadIdx.x, lane = tid & 63, wave = tid >> 6;
    int quad = lane >> 4, l16 = lane & 15;
    int wm = wave & 1, wn = wave >> 1;
    f32x4 acc[4][4];
    f32x4 z4 = {0.f, 0.f, 0.f, 0.f};
    for (int mt = 0; mt < 4; mt++) for (int nt = 0; nt < 4; nt++) acc[mt][nt] = z4;

    int srow = tid >> 1, scol = (tid & 1) * 16;
    const unsigned short* hb = hT + (size_t)b * T_ * C_;
    for (int dk = 0; dk < 5; dk++) {
        int trow = t0 + dk - 2 + srow;
        bool inb = (unsigned)trow < (unsigned)T_;
        const unsigned short* bsrc = hb + (size_t)trow * C_ + scol;
        const unsigned short* asrc = wp + (size_t)(m0 + srow) * 2560 + dk * 512 + scol;
        for (int ci0 = 0; ci0 < 512; ci0 += 32) {
            __syncthreads();
            uint4 a0 = *(const uint4*)(asrc + ci0);
            uint4 a1 = *(const uint4*)(asrc + ci0 + 8);
            uint4 b0 = make_uint4(0, 0, 0, 0), b1 = make_uint4(0, 0, 0, 0);
            if (inb) { b0 = *(const uint4*)(bsrc + ci0); b1 = *(const uint4*)(bsrc + ci0 + 8); }
            *(uint4*)&As[srow * 32 + scol]     = a0;
            *(uint4*)&As[srow * 32 + scol + 8] = a1;
            *(uint4*)&Bs[srow * 32 + scol]     = b0;
            *(uint4*)&Bs[srow * 32 + scol + 8] = b1;
            __syncthreads();
            bf16x8 af[4], bfr[4];
            for (int mt = 0; mt < 4; mt++) af[mt]  = *(const bf16x8*)&As[(wm * 64 + mt * 16 + l16) * 32 + quad * 8];
            for (int nt = 0; nt < 4; nt++) bfr[nt] = *(const bf16x8*)&Bs[(wn * 64 + nt * 16 + l16) * 32 + quad * 8];
            for (int mt = 0; mt < 4; mt++)
                for (int nt = 0; nt < 4; nt++)
                    acc[mt][nt] = __builtin_amdgcn_mfma_f32_16x16x32_bf16(af[mt], bfr[nt], acc[mt][nt], 0, 0, 0);
        }
    }
    for (int mt = 0; mt < 4; mt++) {
        int cobase = m0 + wm * 64 + mt * 16 + quad * 4;
        for (int nt = 0; nt < 4; nt++) {
            int t = t0 + wn * 64 + nt * 16 + l16;
            for (int r = 0; r < 4; r++) {
                int co = cobase + r;
                size_t idx = ((size_t)(b * C_ + co)) * T_ + t;
                out[idx] = acc[mt][nt][r] + bias[co] + x[idx];
            }
        }
    }
}

// ---------------- launch ----------------
extern "C" void kernel_launch(void* const* d_in, const int* in_sizes, int n_in,
                              void* d_out, int out_size, void* d_ws, size_t ws_size,
                              hipStream_t stream) {
    const float* x      = (const float*)d_in[0];
    const float* gamma  = (const float*)d_in[1];
    const float* beta   = (const float*)d_in[2];
    const float* qkv_w  = (const float*)d_in[3];
    const float* qkv_b  = (const float*)d_in[4];
    const float* proj_w = (const float*)d_in[5];
    const float* proj_b = (const float*)d_in[6];
    float* out = (float*)d_out;
    char* ws = (char*)d_ws;

    unsigned short* gnT    = (unsigned short*)(ws);               // 16 MiB  [4][4096][512]
    unsigned short* wqkvT  = (unsigned short*)(ws + 16777216);    // 48 MiB  [1536][32][512]
    unsigned short* wprojT = (unsigned short*)(ws + 67108864);    // 2.5 MiB [512][5][512]
    unsigned short* qTb    = (unsigned short*)(ws + 69730304);    // 16 MiB  [16][4096][128]
    unsigned short* kTb    = (unsigned short*)(ws + 86507520);    // 16 MiB
    unsigned short* vb     = (unsigned short*)(ws + 103284736);   // 16 MiB  [16][128][4096]
    unsigned short* hT     = gnT;  // reuse: gnT dead after gemm_qkv

    hipLaunchKernelGGL(cvt_wqkv,  dim3(1536),     dim3(256),  0, stream, qkv_w, wqkvT);
    hipLaunchKernelGGL(cvt_wproj, dim3(512),      dim3(256),  0, stream, proj_w, wprojT);
    hipLaunchKernelGGL(groupnorm, dim3(32, 4),    dim3(1024), 0, stream, x, gamma, beta, gnT);
    hipLaunchKernelGGL(gemm_qkv,  dim3(32, 12, 4), dim3(256), 0, stream, gnT, wqkvT, qkv_b, qTb, kTb, vb);
    hipLaunchKernelGGL(attn,      dim3(64, 16),   dim3(256),  0, stream, qTb, kTb, vb, hT);
    hipLaunchKernelGGL(gemm_proj, dim3(32, 4, 4), dim3(256),  0, stream, hT, wprojT, proj_b, x, out);
}

// Round 2
// 1708.398 us; speedup vs baseline: 1.1691x; 1.1691x over previous
//
#include <hip/hip_runtime.h>
#include <hip/hip_bf16.h>
#include <math.h>

// ---------------- types / helpers ----------------
typedef __attribute__((ext_vector_type(8))) __bf16 bf16x8;
typedef __attribute__((ext_vector_type(4))) float  f32x4;

__device__ __forceinline__ unsigned short f2bf(float f) {
    union { float f; unsigned int u; } x; x.f = f;
    unsigned int r = x.u + 0x7fffu + ((x.u >> 16) & 1u);   // RTNE
    return (unsigned short)(r >> 16);
}

// async global->LDS, 16B per lane; LDS dest = wave-uniform base + lane*16
__device__ __forceinline__ void gl_lds16(const unsigned short* g, unsigned short* l) {
    auto gp = (const unsigned int __attribute__((address_space(1)))*)((const void*)g);
    auto lp = (unsigned int __attribute__((address_space(3)))*)(unsigned int)(unsigned long long)((void*)l);
    __builtin_amdgcn_global_load_lds(gp, lp, 16, 0, 0);
}

#define B_   4
#define C_   512
#define T_   4096
#define NH   4
#define DH   128

// ---------------- weight converts (permute [co][ci][k] -> [co][k][ci], fp32->bf16) ----------------
__global__ __launch_bounds__(256) void cvt_wqkv(const float* __restrict__ w, unsigned short* __restrict__ o) {
    __shared__ unsigned short l[512 * 33];
    int co = blockIdx.x;
    const float* src = w + (size_t)co * 16384;
    for (int j = 0; j < 64; j++) {
        int i = threadIdx.x + j * 256;              // i = ci*32 + dk
        l[(i >> 5) * 33 + (i & 31)] = f2bf(src[i]);
    }
    __syncthreads();
    unsigned short* dst = o + (size_t)co * 16384;
    for (int j = 0; j < 64; j++) {
        int i = threadIdx.x + j * 256;              // i = dk*512 + ci
        int dk = i >> 9, ci = i & 511;
        dst[i] = l[ci * 33 + dk];
    }
}

__global__ __launch_bounds__(256) void cvt_wproj(const float* __restrict__ w, unsigned short* __restrict__ o) {
    __shared__ unsigned short l[512 * 6];
    int co = blockIdx.x;
    const float* src = w + (size_t)co * 2560;
    for (int j = 0; j < 10; j++) {
        int i = threadIdx.x + j * 256;              // i = ci*5 + dk
        int ci = i / 5, dk = i - ci * 5;
        l[ci * 6 + dk] = f2bf(src[i]);
    }
    __syncthreads();
    unsigned short* dst = o + (size_t)co * 2560;
    for (int j = 0; j < 10; j++) {
        int i = threadIdx.x + j * 256;              // i = dk*512 + ci
        int dk = i >> 9, ci = i & 511;
        dst[i] = l[ci * 6 + dk];
    }
}

// ---------------- GroupNorm -> bf16, stored t-major gnT[b][t][c] ----------------
__global__ __launch_bounds__(1024) void groupnorm(const float* __restrict__ x,
                                                  const float* __restrict__ gamma,
                                                  const float* __restrict__ beta,
                                                  unsigned short* __restrict__ gnT) {
    int g = blockIdx.x, b = blockIdx.y;
    int tid = threadIdx.x;
    const float* base = x + ((size_t)b * C_ + g * 16) * T_;
    float s = 0.f, s2 = 0.f;
    const float4* b4 = (const float4*)base;
    for (int j = 0; j < 16; j++) {
        float4 v = b4[tid + j * 1024];
        s  += v.x + v.y + v.z + v.w;
        s2 += v.x * v.x + v.y * v.y + v.z * v.z + v.w * v.w;
    }
    for (int off = 32; off; off >>= 1) { s += __shfl_down(s, off, 64); s2 += __shfl_down(s2, off, 64); }
    __shared__ float red[34];
    int wid = tid >> 6, lane = tid & 63;
    if (lane == 0) { red[wid] = s; red[16 + wid] = s2; }
    __syncthreads();
    if (tid == 0) {
        float ts = 0.f, ts2 = 0.f;
        for (int i = 0; i < 16; i++) { ts += red[i]; ts2 += red[16 + i]; }
        float mu = ts / 65536.f;
        float var = ts2 / 65536.f - mu * mu;
        red[32] = mu; red[33] = rsqrtf(var + 1e-5f);
    }
    __syncthreads();
    float mu = red[32], inv = red[33];
    for (int p = 0; p < 4; p++) {
        int t = tid + p * 1024;
        unsigned short outv[16];
        for (int cc = 0; cc < 16; cc++) {
            float xv = base[(size_t)cc * T_ + t];
            int c = g * 16 + cc;
            outv[cc] = f2bf((xv - mu) * inv * gamma[c] + beta[c]);
        }
        unsigned short* dst = gnT + ((size_t)b * T_ + t) * C_ + g * 16;
        *(uint4*)dst       = *(uint4*)outv;
        *(uint4*)(dst + 8) = *(uint4*)(outv + 8);
    }
}

// ---------------- QKV conv as GEMM, BK=64, global_load_lds + XOR swizzle ----------------
// C[co=1536][t=4096] per batch, K = dk(32) x ci(512) flattened (uniform stride 64/step)
__global__ __launch_bounds__(256, 3) void gemm_qkv(const unsigned short* __restrict__ gnT,
                                                   const unsigned short* __restrict__ wq,   // [co][dk][ci] bf16
                                                   const float* __restrict__ bias,
                                                   unsigned short* __restrict__ qT,
                                                   unsigned short* __restrict__ kT,
                                                   unsigned short* __restrict__ vv) {
    int nblk = blockIdx.x, mblk = blockIdx.y, b = blockIdx.z;
    int m0 = mblk * 128, t0 = nblk * 128;
    __shared__ unsigned short As[128 * 64];   // [m][k], 16B block p of row r holds cols (p^(r&7))*8..+8
    __shared__ unsigned short Bs[128 * 64];   // [n=t][k]
    int tid = threadIdx.x, lane = tid & 63, wave = tid >> 6;
    int quad = lane >> 4, l16 = lane & 15;
    int wm = wave & 1, wn = wave >> 1;

    // staging source addressing (swizzled per-lane)
    int srow8 = lane >> 3;        // row within 8-row group
    int scb = (lane & 7) ^ srow8; // swizzled source col-block
    const unsigned short* gb = gnT + (size_t)b * T_ * C_;
    const unsigned short* ap[4]; const unsigned short* bp[4];
    unsigned short *la[4], *lb[4];
#pragma unroll
    for (int i = 0; i < 4; i++) {
        int g = wave * 4 + i;
        int row = g * 8 + srow8;
        ap[i] = wq + (size_t)(m0 + row) * 16384 + scb * 8;
        bp[i] = gb + ((size_t)(t0 - 15 + row)) * 512 + scb * 8;   // may over-read <=15KB (safe: ws neighbors)
        la[i] = As + g * 512;
        lb[i] = Bs + g * 512;
    }
    // fragment read pointers (constant across K loop)
    const unsigned short* pAr[2]; const unsigned short* pBr[2];
#pragma unroll
    for (int kk = 0; kk < 2; kk++) {
        pAr[kk] = As + (wm * 64 + l16) * 64 + (((kk * 4 + quad) ^ (l16 & 7)) << 3);
        pBr[kk] = Bs + (wn * 64 + l16) * 64 + (((kk * 4 + quad) ^ (l16 & 7)) << 3);
    }
    f32x4 acc[4][4];
    f32x4 z4 = {0.f, 0.f, 0.f, 0.f};
#pragma unroll
    for (int mt = 0; mt < 4; mt++)
#pragma unroll
        for (int nt = 0; nt < 4; nt++) acc[mt][nt] = z4;

    bool isF = (nblk == 0), isL = (nblk == 31);
    for (int s = 0; s < 256; s++) {
        __syncthreads();
#pragma unroll
        for (int i = 0; i < 4; i++) { gl_lds16(ap[i], la[i]); ap[i] += 64; }
#pragma unroll
        for (int i = 0; i < 4; i++) { gl_lds16(bp[i], lb[i]); bp[i] += 64; }
        __syncthreads();
        int dk = s >> 3;
        if (isF && dk < 15) {            // zero rows with t < 0 (block-uniform branch)
            int nz = 15 - dk, r = tid >> 3;
            if (r < nz) *(uint4*)&Bs[(r << 6) + ((tid & 7) << 3)] = make_uint4(0, 0, 0, 0);
            __syncthreads();
        }
        if (isL && dk > 15) {            // zero rows with t >= 4096
            int nb = dk - 15, rr = tid >> 3;
            if (rr < nb) *(uint4*)&Bs[((128 - nb + rr) << 6) + ((tid & 7) << 3)] = make_uint4(0, 0, 0, 0);
            __syncthreads();
        }
#pragma unroll
        for (int kk = 0; kk < 2; kk++) {
            bf16x8 af[4], bfr[4];
#pragma unroll
            for (int mt = 0; mt < 4; mt++) af[mt]  = *(const bf16x8*)(pAr[kk] + mt * 1024);
#pragma unroll
            for (int nt = 0; nt < 4; nt++) bfr[nt] = *(const bf16x8*)(pBr[kk] + nt * 1024);
#pragma unroll
            for (int mt = 0; mt < 4; mt++)
#pragma unroll
                for (int nt = 0; nt < 4; nt++)
                    acc[mt][nt] = __builtin_amdgcn_mfma_f32_16x16x32_bf16(af[mt], bfr[nt], acc[mt][nt], 0, 0, 0);
        }
    }
    // epilogue: bias + bf16 + scatter to q/k/v layouts
#pragma unroll
    for (int mt = 0; mt < 4; mt++) {
        int cobase = m0 + wm * 64 + mt * 16 + quad * 4;
        int h = cobase / 384;
        int local = cobase - h * 384;
        int bh = b * NH + h;
#pragma unroll
        for (int nt = 0; nt < 4; nt++) {
            int t = t0 + wn * 64 + nt * 16 + l16;
            f32x4 a = acc[mt][nt];
            unsigned short r4[4];
            for (int r = 0; r < 4; r++) r4[r] = f2bf(a[r] + bias[cobase + r]);
            if (local < 128) {
                unsigned short* dst = qT + ((size_t)bh * T_ + t) * DH + local;
                *(uint2*)dst = *(uint2*)r4;
            } else if (local < 256) {
                unsigned short* dst = kT + ((size_t)bh * T_ + t) * DH + (local - 128);
                *(uint2*)dst = *(uint2*)r4;
            } else {
                unsigned short* dst = vv + ((size_t)bh * DH + (local - 256)) * T_ + t;
                for (int r = 0; r < 4; r++) dst[(size_t)r * T_] = r4[r];
            }
        }
    }
}

// ---------------- flash attention: 64-query tile, online softmax ----------------
__global__ __launch_bounds__(256) void attn(const unsigned short* __restrict__ qT,
                                            const unsigned short* __restrict__ kT,
                                            const unsigned short* __restrict__ vv,
                                            unsigned short* __restrict__ hT) {
    int q0 = blockIdx.x * 64, bh = blockIdx.y;
    int b = bh >> 2, h = bh & 3;
    __shared__ unsigned short Qs[64 * 128], Ks[64 * 128], Vs[128 * 64], Ps[64 * 64];
    int tid = threadIdx.x, lane = tid & 63, wave = tid >> 6, quad = lane >> 4, l16 = lane & 15;
    {
        int row = tid >> 4, col = (tid & 15) * 8;
        for (int p = 0; p < 4; p++)
            *(uint4*)&Qs[(row + p * 16) * 128 + col] =
                *(const uint4*)&qT[((size_t)bh * T_ + q0 + row + p * 16) * DH + col];
    }
    float m_i[4], l_i[4];
    for (int r = 0; r < 4; r++) { m_i[r] = -1e30f; l_i[r] = 0.f; }
    f32x4 z4 = {0.f, 0.f, 0.f, 0.f};
    f32x4 o[8];
    for (int nt = 0; nt < 8; nt++) o[nt] = z4;
    const float scale2 = 0.08838834764831845f;

    for (int ts0 = 0; ts0 < T_; ts0 += 64) {
        __syncthreads();
        {
            int row = tid >> 4, col = (tid & 15) * 8;
            for (int p = 0; p < 4; p++)
                *(uint4*)&Ks[(row + p * 16) * 128 + col] =
                    *(const uint4*)&kT[((size_t)bh * T_ + ts0 + row + p * 16) * DH + col];
            int c = tid >> 3, col2 = (tid & 7) * 8;
            for (int p = 0; p < 4; p++)
                *(uint4*)&Vs[(c + p * 32) * 64 + col2] =
                    *(const uint4*)&vv[((size_t)bh * DH + c + p * 32) * T_ + ts0 + col2];
        }
        __syncthreads();
        f32x4 s[4];
        for (int nt = 0; nt < 4; nt++) s[nt] = z4;
        for (int kk = 0; kk < 4; kk++) {
            bf16x8 af = *(const bf16x8*)&Qs[(wave * 16 + l16) * 128 + kk * 32 + quad * 8];
            for (int nt = 0; nt < 4; nt++) {
                bf16x8 bfr = *(const bf16x8*)&Ks[(nt * 16 + l16) * 128 + kk * 32 + quad * 8];
                s[nt] = __builtin_amdgcn_mfma_f32_16x16x32_bf16(af, bfr, s[nt], 0, 0, 0);
            }
        }
        for (int nt = 0; nt < 4; nt++) s[nt] *= scale2;
        for (int r = 0; r < 4; r++) {
            float mx = fmaxf(fmaxf(s[0][r], s[1][r]), fmaxf(s[2][r], s[3][r]));
            for (int off = 1; off < 16; off <<= 1) mx = fmaxf(mx, __shfl_xor(mx, off, 64));
            float mnew = fmaxf(m_i[r], mx);
            float alpha = __expf(m_i[r] - mnew);
            m_i[r] = mnew;
            float rs = 0.f;
            for (int nt = 0; nt < 4; nt++) { float p = __expf(s[nt][r] - mnew); s[nt][r] = p; rs += p; }
            for (int off = 1; off < 16; off <<= 1) rs += __shfl_xor(rs, off, 64);
            l_i[r] = l_i[r] * alpha + rs;
            for (int nt = 0; nt < 8; nt++) o[nt][r] *= alpha;
            int prow = wave * 16 + quad * 4 + r;
            for (int nt = 0; nt < 4; nt++) Ps[prow * 64 + nt * 16 + l16] = f2bf(s[nt][r]);
        }
        __syncthreads();
        for (int kk = 0; kk < 2; kk++) {
            bf16x8 af = *(const bf16x8*)&Ps[(wave * 16 + l16) * 64 + kk * 32 + quad * 8];
            for (int nt = 0; nt < 8; nt++) {
                bf16x8 bfr = *(const bf16x8*)&Vs[(nt * 16 + l16) * 64 + kk * 32 + quad * 8];
                o[nt] = __builtin_amdgcn_mfma_f32_16x16x32_bf16(af, bfr, o[nt], 0, 0, 0);
            }
        }
    }
    for (int r = 0; r < 4; r++) {
        float invl = 1.0f / l_i[r];
        int t = q0 + wave * 16 + quad * 4 + r;
        unsigned short* dst = hT + ((size_t)b * T_ + t) * C_ + h * DH;
        for (int nt = 0; nt < 8; nt++) dst[nt * 16 + l16] = f2bf(o[nt][r] * invl);
    }
}

// ---------------- proj conv as GEMM (k=5), BK=64, same staging structure ----------------
__global__ __launch_bounds__(256, 3) void gemm_proj(const unsigned short* __restrict__ hT,
                                                    const unsigned short* __restrict__ wp,   // [co][dk(5)][ci] bf16
                                                    const float* __restrict__ bias,
                                                    const float* __restrict__ x,
                                                    float* __restrict__ out) {
    int nblk = blockIdx.x, mblk = blockIdx.y, b = blockIdx.z;
    int m0 = mblk * 128, t0 = nblk * 128;
    __shared__ unsigned short As[128 * 64], Bs[128 * 64];
    int tid = threadIdx.x, lane = tid & 63, wave = tid >> 6;
    int quad = lane >> 4, l16 = lane & 15;
    int wm = wave & 1, wn = wave >> 1;

    int srow8 = lane >> 3;
    int scb = (lane & 7) ^ srow8;
    const unsigned short* hb = hT + (size_t)b * T_ * C_;
    const unsigned short* ap[4]; const unsigned short* bp[4];
    unsigned short *la[4], *lb[4];
#pragma unroll
    for (int i = 0; i < 4; i++) {
        int g = wave * 4 + i;
        int row = g * 8 + srow8;
        ap[i] = wp + (size_t)(m0 + row) * 2560 + scb * 8;
        bp[i] = hb + ((size_t)(t0 - 2 + row)) * 512 + scb * 8;
        la[i] = As + g * 512;
        lb[i] = Bs + g * 512;
    }
    const unsigned short* pAr[2]; const unsigned short* pBr[2];
#pragma unroll
    for (int kk = 0; kk < 2; kk++) {
        pAr[kk] = As + (wm * 64 + l16) * 64 + (((kk * 4 + quad) ^ (l16 & 7)) << 3);
        pBr[kk] = Bs + (wn * 64 + l16) * 64 + (((kk * 4 + quad) ^ (l16 & 7)) << 3);
    }
    f32x4 acc[4][4];
    f32x4 z4 = {0.f, 0.f, 0.f, 0.f};
#pragma unroll
    for (int mt = 0; mt < 4; mt++)
#pragma unroll
        for (int nt = 0; nt < 4; nt++) acc[mt][nt] = z4;

    bool isF = (nblk == 0), isL = (nblk == 31);
    for (int s = 0; s < 40; s++) {
        __syncthreads();
#pragma unroll
        for (int i = 0; i < 4; i++) { gl_lds16(ap[i], la[i]); ap[i] += 64; }
#pragma unroll
        for (int i = 0; i < 4; i++) { gl_lds16(bp[i], lb[i]); bp[i] += 64; }
        __syncthreads();
        int dk = s >> 3;
        if (isF && dk < 2) {
            int nz = 2 - dk, r = tid >> 3;
            if (r < nz) *(uint4*)&Bs[(r << 6) + ((tid & 7) << 3)] = make_uint4(0, 0, 0, 0);
            __syncthreads();
        }
        if (isL && dk > 2) {
            int nb = dk - 2, rr = tid >> 3;
            if (rr < nb) *(uint4*)&Bs[((128 - nb + rr) << 6) + ((tid & 7) << 3)] = make_uint4(0, 0, 0, 0);
            __syncthreads();
        }
#pragma unroll
        for (int kk = 0; kk < 2; kk++) {
            bf16x8 af[4], bfr[4];
#pragma unroll
            for (int mt = 0; mt < 4; mt++) af[mt]  = *(const bf16x8*)(pAr[kk] + mt * 1024);
#pragma unroll
            for (int nt = 0; nt < 4; nt++) bfr[nt] = *(const bf16x8*)(pBr[kk] + nt * 1024);
#pragma unroll
            for (int mt = 0; mt < 4; mt++)
#pragma unroll
                for (int nt = 0; nt < 4; nt++)
                    acc[mt][nt] = __builtin_amdgcn_mfma_f32_16x16x32_bf16(af[mt], bfr[nt], acc[mt][nt], 0, 0, 0);
        }
    }
#pragma unroll
    for (int mt = 0; mt < 4; mt++) {
        int cobase = m0 + wm * 64 + mt * 16 + quad * 4;
#pragma unroll
        for (int nt = 0; nt < 4; nt++) {
            int t = t0 + wn * 64 + nt * 16 + l16;
            for (int r = 0; r < 4; r++) {
                int co = cobase + r;
                size_t idx = ((size_t)(b * C_ + co)) * T_ + t;
                out[idx] = acc[mt][nt][r] + bias[co] + x[idx];
            }
        }
    }
}

// ---------------- launch ----------------
extern "C" void kernel_launch(void* const* d_in, const int* in_sizes, int n_in,
                              void* d_out, int out_size, void* d_ws, size_t ws_size,
                              hipStream_t stream) {
    const float* x      = (const float*)d_in[0];
    const float* gamma  = (const float*)d_in[1];
    const float* beta   = (const float*)d_in[2];
    const float* qkv_w  = (const float*)d_in[3];
    const float* qkv_b  = (const float*)d_in[4];
    const float* proj_w = (const float*)d_in[5];
    const float* proj_b = (const float*)d_in[6];
    float* out = (float*)d_out;
    char* ws = (char*)d_ws;

    // order matters: gnT/hT sits between wprojT and qTb so that +/-15-row
    // halo over-reads from edge tiles stay inside the workspace.
    unsigned short* wqkvT  = (unsigned short*)(ws);               // 48 MiB  [1536][32][512]
    unsigned short* wprojT = (unsigned short*)(ws + 50331648);    // 2.5 MiB [512][5][512]
    unsigned short* gnT    = (unsigned short*)(ws + 52953088);    // 16 MiB  [4][4096][512]
    unsigned short* qTb    = (unsigned short*)(ws + 69730304);    // 16 MiB  [16][4096][128]
    unsigned short* kTb    = (unsigned short*)(ws + 86507520);    // 16 MiB
    unsigned short* vb     = (unsigned short*)(ws + 103284736);   // 16 MiB  [16][128][4096]
    unsigned short* hT     = gnT;  // reuse: gnT dead after gemm_qkv

    hipLaunchKernelGGL(cvt_wqkv,  dim3(1536),      dim3(256),  0, stream, qkv_w, wqkvT);
    hipLaunchKernelGGL(cvt_wproj, dim3(512),       dim3(256),  0, stream, proj_w, wprojT);
    hipLaunchKernelGGL(groupnorm, dim3(32, 4),     dim3(1024), 0, stream, x, gamma, beta, gnT);
    hipLaunchKernelGGL(gemm_qkv,  dim3(32, 12, 4), dim3(256),  0, stream, gnT, wqkvT, qkv_b, qTb, kTb, vb);
    hipLaunchKernelGGL(attn,      dim3(64, 16),    dim3(256),  0, stream, qTb, kTb, vb, hT);
    hipLaunchKernelGGL(gemm_proj, dim3(32, 4, 4),  dim3(256),  0, stream, hT, wprojT, proj_b, x, out);
}

// Round 3
// 1267.798 us; speedup vs baseline: 1.5754x; 1.3475x over previous
//
#include <hip/hip_runtime.h>
#include <hip/hip_bf16.h>
#include <math.h>

// ---------------- types / helpers ----------------
typedef __attribute__((ext_vector_type(8))) __bf16 bf16x8;
typedef __attribute__((ext_vector_type(4))) float  f32x4;

__device__ __forceinline__ unsigned short f2bf(float f) {
    union { float f; unsigned int u; } x; x.f = f;
    unsigned int r = x.u + 0x7fffu + ((x.u >> 16) & 1u);   // RTNE
    return (unsigned short)(r >> 16);
}

// async global->LDS, 16B per lane; LDS dest = wave-uniform base + lane*16
__device__ __forceinline__ void gl_lds16(const unsigned short* g, unsigned short* l) {
    auto gp = (const unsigned int __attribute__((address_space(1)))*)((const void*)g);
    auto lp = (unsigned int __attribute__((address_space(3)))*)(unsigned int)(unsigned long long)((void*)l);
    __builtin_amdgcn_global_load_lds(gp, lp, 16, 0, 0);
}

#define B_   4
#define C_   512
#define T_   4096
#define NH   4
#define DH   128

// ---------------- weight converts (permute [co][ci][k] -> [co][k][ci], fp32->bf16) ----------------
__global__ __launch_bounds__(256) void cvt_wqkv(const float* __restrict__ w, unsigned short* __restrict__ o) {
    __shared__ unsigned short l[512 * 33];
    int co = blockIdx.x;
    const float* src = w + (size_t)co * 16384;
    for (int j = 0; j < 64; j++) {
        int i = threadIdx.x + j * 256;              // i = ci*32 + dk
        l[(i >> 5) * 33 + (i & 31)] = f2bf(src[i]);
    }
    __syncthreads();
    unsigned short* dst = o + (size_t)co * 16384;
    for (int j = 0; j < 64; j++) {
        int i = threadIdx.x + j * 256;              // i = dk*512 + ci
        int dk = i >> 9, ci = i & 511;
        dst[i] = l[ci * 33 + dk];
    }
}

__global__ __launch_bounds__(256) void cvt_wproj(const float* __restrict__ w, unsigned short* __restrict__ o) {
    __shared__ unsigned short l[512 * 6];
    int co = blockIdx.x;
    const float* src = w + (size_t)co * 2560;
    for (int j = 0; j < 10; j++) {
        int i = threadIdx.x + j * 256;              // i = ci*5 + dk
        int ci = i / 5, dk = i - ci * 5;
        l[ci * 6 + dk] = f2bf(src[i]);
    }
    __syncthreads();
    unsigned short* dst = o + (size_t)co * 2560;
    for (int j = 0; j < 10; j++) {
        int i = threadIdx.x + j * 256;              // i = dk*512 + ci
        int dk = i >> 9, ci = i & 511;
        dst[i] = l[ci * 6 + dk];
    }
}

// ---------------- GroupNorm -> bf16, stored t-major gnT[b][t][c] ----------------
__global__ __launch_bounds__(1024) void groupnorm(const float* __restrict__ x,
                                                  const float* __restrict__ gamma,
                                                  const float* __restrict__ beta,
                                                  unsigned short* __restrict__ gnT) {
    int g = blockIdx.x, b = blockIdx.y;
    int tid = threadIdx.x;
    const float* base = x + ((size_t)b * C_ + g * 16) * T_;
    float s = 0.f, s2 = 0.f;
    const float4* b4 = (const float4*)base;
    for (int j = 0; j < 16; j++) {
        float4 v = b4[tid + j * 1024];
        s  += v.x + v.y + v.z + v.w;
        s2 += v.x * v.x + v.y * v.y + v.z * v.z + v.w * v.w;
    }
    for (int off = 32; off; off >>= 1) { s += __shfl_down(s, off, 64); s2 += __shfl_down(s2, off, 64); }
    __shared__ float red[34];
    int wid = tid >> 6, lane = tid & 63;
    if (lane == 0) { red[wid] = s; red[16 + wid] = s2; }
    __syncthreads();
    if (tid == 0) {
        float ts = 0.f, ts2 = 0.f;
        for (int i = 0; i < 16; i++) { ts += red[i]; ts2 += red[16 + i]; }
        float mu = ts / 65536.f;
        float var = ts2 / 65536.f - mu * mu;
        red[32] = mu; red[33] = rsqrtf(var + 1e-5f);
    }
    __syncthreads();
    float mu = red[32], inv = red[33];
    for (int p = 0; p < 4; p++) {
        int t = tid + p * 1024;
        unsigned short outv[16];
        for (int cc = 0; cc < 16; cc++) {
            float xv = base[(size_t)cc * T_ + t];
            int c = g * 16 + cc;
            outv[cc] = f2bf((xv - mu) * inv * gamma[c] + beta[c]);
        }
        unsigned short* dst = gnT + ((size_t)b * T_ + t) * C_ + g * 16;
        *(uint4*)dst       = *(uint4*)outv;
        *(uint4*)(dst + 8) = *(uint4*)(outv + 8);
    }
}

// ---------------- QKV conv as GEMM, BK=64, global_load_lds + XOR swizzle ----------------
__global__ __launch_bounds__(256, 3) void gemm_qkv(const unsigned short* __restrict__ gnT,
                                                   const unsigned short* __restrict__ wq,   // [co][dk][ci] bf16
                                                   const float* __restrict__ bias,
                                                   unsigned short* __restrict__ qT,
                                                   unsigned short* __restrict__ kT,
                                                   unsigned short* __restrict__ vv) {
    int nblk = blockIdx.x, mblk = blockIdx.y, b = blockIdx.z;
    int m0 = mblk * 128, t0 = nblk * 128;
    __shared__ unsigned short As[128 * 64];   // 16B block p of row r holds cols (p^(r&7))*8..+8
    __shared__ unsigned short Bs[128 * 64];
    int tid = threadIdx.x, lane = tid & 63, wave = tid >> 6;
    int quad = lane >> 4, l16 = lane & 15;
    int wm = wave & 1, wn = wave >> 1;

    int srow8 = lane >> 3;
    int scb = (lane & 7) ^ srow8;
    const unsigned short* gb = gnT + (size_t)b * T_ * C_;
    const unsigned short* ap[4]; const unsigned short* bp[4];
    unsigned short *la[4], *lb[4];
#pragma unroll
    for (int i = 0; i < 4; i++) {
        int g = wave * 4 + i;
        int row = g * 8 + srow8;
        ap[i] = wq + (size_t)(m0 + row) * 16384 + scb * 8;
        bp[i] = gb + ((size_t)(t0 - 15 + row)) * 512 + scb * 8;   // halo over-read stays in ws
        la[i] = As + g * 512;
        lb[i] = Bs + g * 512;
    }
    const unsigned short* pAr[2]; const unsigned short* pBr[2];
#pragma unroll
    for (int kk = 0; kk < 2; kk++) {
        pAr[kk] = As + (wm * 64 + l16) * 64 + (((kk * 4 + quad) ^ (l16 & 7)) << 3);
        pBr[kk] = Bs + (wn * 64 + l16) * 64 + (((kk * 4 + quad) ^ (l16 & 7)) << 3);
    }
    f32x4 acc[4][4];
    f32x4 z4 = {0.f, 0.f, 0.f, 0.f};
#pragma unroll
    for (int mt = 0; mt < 4; mt++)
#pragma unroll
        for (int nt = 0; nt < 4; nt++) acc[mt][nt] = z4;

    bool isF = (nblk == 0), isL = (nblk == 31);
    for (int s = 0; s < 256; s++) {
        __syncthreads();
#pragma unroll
        for (int i = 0; i < 4; i++) { gl_lds16(ap[i], la[i]); ap[i] += 64; }
#pragma unroll
        for (int i = 0; i < 4; i++) { gl_lds16(bp[i], lb[i]); bp[i] += 64; }
        __syncthreads();
        int dk = s >> 3;
        if (isF && dk < 15) {
            int nz = 15 - dk, r = tid >> 3;
            if (r < nz) *(uint4*)&Bs[(r << 6) + ((tid & 7) << 3)] = make_uint4(0, 0, 0, 0);
            __syncthreads();
        }
        if (isL && dk > 15) {
            int nb = dk - 15, rr = tid >> 3;
            if (rr < nb) *(uint4*)&Bs[((128 - nb + rr) << 6) + ((tid & 7) << 3)] = make_uint4(0, 0, 0, 0);
            __syncthreads();
        }
#pragma unroll
        for (int kk = 0; kk < 2; kk++) {
            bf16x8 af[4], bfr[4];
#pragma unroll
            for (int mt = 0; mt < 4; mt++) af[mt]  = *(const bf16x8*)(pAr[kk] + mt * 1024);
#pragma unroll
            for (int nt = 0; nt < 4; nt++) bfr[nt] = *(const bf16x8*)(pBr[kk] + nt * 1024);
#pragma unroll
            for (int mt = 0; mt < 4; mt++)
#pragma unroll
                for (int nt = 0; nt < 4; nt++)
                    acc[mt][nt] = __builtin_amdgcn_mfma_f32_16x16x32_bf16(af[mt], bfr[nt], acc[mt][nt], 0, 0, 0);
        }
    }
#pragma unroll
    for (int mt = 0; mt < 4; mt++) {
        int cobase = m0 + wm * 64 + mt * 16 + quad * 4;
        int h = cobase / 384;
        int local = cobase - h * 384;
        int bh = b * NH + h;
#pragma unroll
        for (int nt = 0; nt < 4; nt++) {
            int t = t0 + wn * 64 + nt * 16 + l16;
            f32x4 a = acc[mt][nt];
            unsigned short r4[4];
            for (int r = 0; r < 4; r++) r4[r] = f2bf(a[r] + bias[cobase + r]);
            if (local < 128) {
                unsigned short* dst = qT + ((size_t)bh * T_ + t) * DH + local;
                *(uint2*)dst = *(uint2*)r4;
            } else if (local < 256) {
                unsigned short* dst = kT + ((size_t)bh * T_ + t) * DH + (local - 128);
                *(uint2*)dst = *(uint2*)r4;
            } else {
                unsigned short* dst = vv + ((size_t)bh * DH + (local - 256)) * T_ + t;
                for (int r = 0; r < 4; r++) dst[(size_t)r * T_] = r4[r];
            }
        }
    }
}

// ---------------- flash attention v2: transposed scores, swizzled LDS, async staging ----------------
// per block: 64 queries; per wave: 16 queries. S^T = K·Q^T so softmax is per-lane.
__global__ __launch_bounds__(256, 3) void attn(const unsigned short* __restrict__ qT,
                                               const unsigned short* __restrict__ kT,
                                               const unsigned short* __restrict__ vv,
                                               unsigned short* __restrict__ hT) {
    int q0 = blockIdx.x * 64, bh = blockIdx.y;
    int b = bh >> 2, h = bh & 3;
    __shared__ unsigned short Ks[64 * 128];   // [key][ch], 16B block p of row r = src cols (p^(r&7))*8
    __shared__ unsigned short Vs[128 * 64];   // [ch][key], same swizzle
    __shared__ unsigned short Ps[64 * 72];    // [q][key], pad to 72 shorts
    int tid = threadIdx.x, lane = tid & 63, wave = tid >> 6, quad = lane >> 4, l16 = lane & 15;

    // Q fragments (B-operand: n=l16 -> query, k=quad*8.. within kk*32), loaded once from global
    bf16x8 bq[4];
    {
        const unsigned short* qrow = qT + ((size_t)bh * T_ + q0 + wave * 16 + l16) * DH + quad * 8;
#pragma unroll
        for (int kk = 0; kk < 4; kk++) bq[kk] = *(const bf16x8*)(qrow + kk * 32);
    }

    const unsigned short* kbase = kT + (size_t)bh * T_ * DH;
    const unsigned short* vbase = vv + (size_t)bh * DH * T_;
    int krow_in = lane >> 4, kp = lane & 15;      // K: 16 lanes per 128-short row
    int vrow_in = lane >> 3, vp = lane & 7;       // V: 8 lanes per 64-short row

    float m_i = -1e30f, l_i = 0.f;
    f32x4 z4 = {0.f, 0.f, 0.f, 0.f};
    f32x4 o[8];
#pragma unroll
    for (int nt = 0; nt < 8; nt++) o[nt] = z4;
    const float scale2 = 0.08838834764831845f;    // 1/sqrt(128)

    for (int ts0 = 0; ts0 < T_; ts0 += 64) {
        __syncthreads();
#pragma unroll
        for (int i = 0; i < 4; i++) {             // stage K: 4 rows per instr
            int row = (wave * 4 + i) * 4 + krow_in;
            gl_lds16(kbase + ((size_t)(ts0 + row)) * DH + (((kp ^ (row & 7)) << 3)),
                     Ks + (wave * 4 + i) * 512);
        }
#pragma unroll
        for (int i = 0; i < 4; i++) {             // stage V: 8 rows per instr
            int row = (wave * 4 + i) * 8 + vrow_in;
            gl_lds16(vbase + (size_t)row * T_ + ts0 + (((vp ^ (row & 7)) << 3)),
                     Vs + (wave * 4 + i) * 512);
        }
        __syncthreads();

        // S^T tile: rows = 64 keys (4 mt), cols = this wave's 16 queries
        f32x4 s[4];
#pragma unroll
        for (int mt = 0; mt < 4; mt++) s[mt] = z4;
#pragma unroll
        for (int kk = 0; kk < 4; kk++) {
            int pb = (((kk * 4 + quad) ^ (l16 & 7)) << 3);
#pragma unroll
            for (int mt = 0; mt < 4; mt++) {
                bf16x8 ak = *(const bf16x8*)&Ks[(mt * 16 + l16) * 128 + pb];
                s[mt] = __builtin_amdgcn_mfma_f32_16x16x32_bf16(ak, bq[kk], s[mt], 0, 0, 0);
            }
        }
        // per-lane online softmax for query l16 (replicated across quads)
        float mx = -1e30f;
#pragma unroll
        for (int mt = 0; mt < 4; mt++) {
            s[mt] *= scale2;
            mx = fmaxf(mx, fmaxf(fmaxf(s[mt][0], s[mt][1]), fmaxf(s[mt][2], s[mt][3])));
        }
        mx = fmaxf(mx, __shfl_xor(mx, 16, 64));
        mx = fmaxf(mx, __shfl_xor(mx, 32, 64));
        float mnew = fmaxf(m_i, mx);
        float alpha = __expf(m_i - mnew);
        float rs = 0.f;
#pragma unroll
        for (int mt = 0; mt < 4; mt++) {
#pragma unroll
            for (int r = 0; r < 4; r++) { float p = __expf(s[mt][r] - mnew); s[mt][r] = p; rs += p; }
        }
        rs += __shfl_xor(rs, 16, 64);
        rs += __shfl_xor(rs, 32, 64);
        m_i = mnew;
        l_i = l_i * alpha + rs;
        // write P^T -> Ps[q][key] (wave-private rows; keys quad*4+r contiguous -> uint2)
#pragma unroll
        for (int mt = 0; mt < 4; mt++) {
            unsigned short t4[4];
#pragma unroll
            for (int r = 0; r < 4; r++) t4[r] = f2bf(s[mt][r]);
            *(uint2*)&Ps[(wave * 16 + l16) * 72 + mt * 16 + quad * 4] = *(uint2*)t4;
        }
        // rescale O by alpha (broadcast col-layout -> row-layout)
        float a0 = __shfl(alpha, quad * 4 + 0, 64);
        float a1 = __shfl(alpha, quad * 4 + 1, 64);
        float a2 = __shfl(alpha, quad * 4 + 2, 64);
        float a3 = __shfl(alpha, quad * 4 + 3, 64);
        f32x4 av = {a0, a1, a2, a3};
#pragma unroll
        for (int nt = 0; nt < 8; nt++) o[nt] *= av;
        // PV: A = Ps rows (wave's queries, same-wave data), B = Vs (swizzled)
#pragma unroll
        for (int kk = 0; kk < 2; kk++) {
            bf16x8 ap = *(const bf16x8*)&Ps[(wave * 16 + l16) * 72 + kk * 32 + quad * 8];
            int pb = (((kk * 4 + quad) ^ (l16 & 7)) << 3);
#pragma unroll
            for (int nt = 0; nt < 8; nt++) {
                bf16x8 bv = *(const bf16x8*)&Vs[(nt * 16 + l16) * 64 + pb];
                o[nt] = __builtin_amdgcn_mfma_f32_16x16x32_bf16(ap, bv, o[nt], 0, 0, 0);
            }
        }
    }
    float i0 = 1.f / __shfl(l_i, quad * 4 + 0, 64);
    float i1 = 1.f / __shfl(l_i, quad * 4 + 1, 64);
    float i2 = 1.f / __shfl(l_i, quad * 4 + 2, 64);
    float i3 = 1.f / __shfl(l_i, quad * 4 + 3, 64);
    f32x4 iv = {i0, i1, i2, i3};
#pragma unroll
    for (int r = 0; r < 4; r++) {
        int t = q0 + wave * 16 + quad * 4 + r;
        unsigned short* dst = hT + ((size_t)b * T_ + t) * C_ + h * DH;
#pragma unroll
        for (int nt = 0; nt < 8; nt++) dst[nt * 16 + l16] = f2bf(o[nt][r] * iv[r]);
    }
}

// ---------------- proj conv as GEMM (k=5), BK=64 ----------------
__global__ __launch_bounds__(256, 3) void gemm_proj(const unsigned short* __restrict__ hT,
                                                    const unsigned short* __restrict__ wp,
                                                    const float* __restrict__ bias,
                                                    const float* __restrict__ x,
                                                    float* __restrict__ out) {
    int nblk = blockIdx.x, mblk = blockIdx.y, b = blockIdx.z;
    int m0 = mblk * 128, t0 = nblk * 128;
    __shared__ unsigned short As[128 * 64], Bs[128 * 64];
    int tid = threadIdx.x, lane = tid & 63, wave = tid >> 6;
    int quad = lane >> 4, l16 = lane & 15;
    int wm = wave & 1, wn = wave >> 1;

    int srow8 = lane >> 3;
    int scb = (lane & 7) ^ srow8;
    const unsigned short* hb = hT + (size_t)b * T_ * C_;
    const unsigned short* ap[4]; const unsigned short* bp[4];
    unsigned short *la[4], *lb[4];
#pragma unroll
    for (int i = 0; i < 4; i++) {
        int g = wave * 4 + i;
        int row = g * 8 + srow8;
        ap[i] = wp + (size_t)(m0 + row) * 2560 + scb * 8;
        bp[i] = hb + ((size_t)(t0 - 2 + row)) * 512 + scb * 8;
        la[i] = As + g * 512;
        lb[i] = Bs + g * 512;
    }
    const unsigned short* pAr[2]; const unsigned short* pBr[2];
#pragma unroll
    for (int kk = 0; kk < 2; kk++) {
        pAr[kk] = As + (wm * 64 + l16) * 64 + (((kk * 4 + quad) ^ (l16 & 7)) << 3);
        pBr[kk] = Bs + (wn * 64 + l16) * 64 + (((kk * 4 + quad) ^ (l16 & 7)) << 3);
    }
    f32x4 acc[4][4];
    f32x4 z4 = {0.f, 0.f, 0.f, 0.f};
#pragma unroll
    for (int mt = 0; mt < 4; mt++)
#pragma unroll
        for (int nt = 0; nt < 4; nt++) acc[mt][nt] = z4;

    bool isF = (nblk == 0), isL = (nblk == 31);
    for (int s = 0; s < 40; s++) {
        __syncthreads();
#pragma unroll
        for (int i = 0; i < 4; i++) { gl_lds16(ap[i], la[i]); ap[i] += 64; }
#pragma unroll
        for (int i = 0; i < 4; i++) { gl_lds16(bp[i], lb[i]); bp[i] += 64; }
        __syncthreads();
        int dk = s >> 3;
        if (isF && dk < 2) {
            int nz = 2 - dk, r = tid >> 3;
            if (r < nz) *(uint4*)&Bs[(r << 6) + ((tid & 7) << 3)] = make_uint4(0, 0, 0, 0);
            __syncthreads();
        }
        if (isL && dk > 2) {
            int nb = dk - 2, rr = tid >> 3;
            if (rr < nb) *(uint4*)&Bs[((128 - nb + rr) << 6) + ((tid & 7) << 3)] = make_uint4(0, 0, 0, 0);
            __syncthreads();
        }
#pragma unroll
        for (int kk = 0; kk < 2; kk++) {
            bf16x8 af[4], bfr[4];
#pragma unroll
            for (int mt = 0; mt < 4; mt++) af[mt]  = *(const bf16x8*)(pAr[kk] + mt * 1024);
#pragma unroll
            for (int nt = 0; nt < 4; nt++) bfr[nt] = *(const bf16x8*)(pBr[kk] + nt * 1024);
#pragma unroll
            for (int mt = 0; mt < 4; mt++)
#pragma unroll
                for (int nt = 0; nt < 4; nt++)
                    acc[mt][nt] = __builtin_amdgcn_mfma_f32_16x16x32_bf16(af[mt], bfr[nt], acc[mt][nt], 0, 0, 0);
        }
    }
#pragma unroll
    for (int mt = 0; mt < 4; mt++) {
        int cobase = m0 + wm * 64 + mt * 16 + quad * 4;
#pragma unroll
        for (int nt = 0; nt < 4; nt++) {
            int t = t0 + wn * 64 + nt * 16 + l16;
            for (int r = 0; r < 4; r++) {
                int co = cobase + r;
                size_t idx = ((size_t)(b * C_ + co)) * T_ + t;
                out[idx] = acc[mt][nt][r] + bias[co] + x[idx];
            }
        }
    }
}

// ---------------- launch ----------------
extern "C" void kernel_launch(void* const* d_in, const int* in_sizes, int n_in,
                              void* d_out, int out_size, void* d_ws, size_t ws_size,
                              hipStream_t stream) {
    const float* x      = (const float*)d_in[0];
    const float* gamma  = (const float*)d_in[1];
    const float* beta   = (const float*)d_in[2];
    const float* qkv_w  = (const float*)d_in[3];
    const float* qkv_b  = (const float*)d_in[4];
    const float* proj_w = (const float*)d_in[5];
    const float* proj_b = (const float*)d_in[6];
    float* out = (float*)d_out;
    char* ws = (char*)d_ws;

    unsigned short* wqkvT  = (unsigned short*)(ws);               // 48 MiB  [1536][32][512]
    unsigned short* wprojT = (unsigned short*)(ws + 50331648);    // 2.5 MiB [512][5][512]
    unsigned short* gnT    = (unsigned short*)(ws + 52953088);    // 16 MiB  [4][4096][512]
    unsigned short* qTb    = (unsigned short*)(ws + 69730304);    // 16 MiB  [16][4096][128]
    unsigned short* kTb    = (unsigned short*)(ws + 86507520);    // 16 MiB
    unsigned short* vb     = (unsigned short*)(ws + 103284736);   // 16 MiB  [16][128][4096]
    unsigned short* hT     = gnT;  // reuse: gnT dead after gemm_qkv

    hipLaunchKernelGGL(cvt_wqkv,  dim3(1536),      dim3(256),  0, stream, qkv_w, wqkvT);
    hipLaunchKernelGGL(cvt_wproj, dim3(512),       dim3(256),  0, stream, proj_w, wprojT);
    hipLaunchKernelGGL(groupnorm, dim3(32, 4),     dim3(1024), 0, stream, x, gamma, beta, gnT);
    hipLaunchKernelGGL(gemm_qkv,  dim3(32, 12, 4), dim3(256),  0, stream, gnT, wqkvT, qkv_b, qTb, kTb, vb);
    hipLaunchKernelGGL(attn,      dim3(64, 16),    dim3(256),  0, stream, qTb, kTb, vb, hT);
    hipLaunchKernelGGL(gemm_proj, dim3(32, 4, 4),  dim3(256),  0, stream, hT, wprojT, proj_b, x, out);
}